// Round 1
// baseline (52.196 us; speedup 1.0000x reference)
//
#include <hip/hip_runtime.h>

#define H 4096
#define W 4096
#define R 8              // rows per block
#define TC 4             // cols per thread
#define TPB 256
#define STRIP (TPB*TC)   // 1024 cols per block
#define NSTRIP (W/STRIP) // 4

__global__ __launch_bounds__(TPB)
void wbce_kernel(const float* __restrict__ outp, const float* __restrict__ segp,
                 float* __restrict__ dsum) {
  const int t     = threadIdx.x;
  const int strip = blockIdx.x;
  const int r0    = blockIdx.y * R;
  const int c0    = strip * STRIP + t * TC;

  // double-buffered edge colsums (left edge cs[0], right edge cs[TC-1]) per thread
  __shared__ float eLs[2][TPB], eRs[2][TPB], eLo[2][TPB], eRo[2][TPB];
  // halo columns (raw values) for strip boundaries, rows r0-1 .. r0+R
  __shared__ float hLs[R+2], hRs[R+2], hLo[R+2], hRo[R+2];

  if (t < R + 2) {
    const int rr = r0 - 1 + t;
    const bool rowv = (rr >= 0) && (rr < H);
    const int cL = strip * STRIP - 1;
    const int cR = strip * STRIP + STRIP;
    const bool lv  = rowv && (strip > 0);
    const bool rv  = rowv && (strip < NSTRIP - 1);
    const size_t ro = (size_t)(rowv ? rr : 0) * W;
    hLs[t] = lv ? segp[ro + cL] : 0.f;
    hLo[t] = lv ? outp[ro + cL] : 0.f;
    hRs[t] = rv ? segp[ro + cR] : 0.f;
    hRo[t] = rv ? outp[ro + cR] : 0.f;
  }

  float sa[TC], sb[TC], sc[TC];   // seg rows r-1, r, r+1
  float oa[TC], ob[TC], oc[TC];   // out rows r-1, r, r+1

  auto load4 = [&](const float* __restrict__ p, int ri, float* v) {
    if (ri >= 0 && ri < H) {
      const float4 f = *reinterpret_cast<const float4*>(p + (size_t)ri * W + c0);
      v[0] = f.x; v[1] = f.y; v[2] = f.z; v[3] = f.w;
    } else {
      v[0] = v[1] = v[2] = v[3] = 0.f;
    }
  };

  load4(segp, r0 - 1, sa); load4(outp, r0 - 1, oa);
  load4(segp, r0,     sb); load4(outp, r0,     ob);

  __syncthreads();  // halo LDS visible

  float acc = 0.f;

  #pragma unroll
  for (int i = 0; i < R; ++i) {
    const int r = r0 + i;
    load4(segp, r + 1, sc); load4(outp, r + 1, oc);

    float cs[TC], co[TC];
    #pragma unroll
    for (int k = 0; k < TC; ++k) {
      cs[k] = sa[k] + sb[k] + sc[k];
      co[k] = oa[k] + ob[k] + oc[k];
    }

    const int pb = i & 1;
    eLs[pb][t] = cs[0]; eRs[pb][t] = cs[TC-1];
    eLo[pb][t] = co[0]; eRo[pb][t] = co[TC-1];
    __syncthreads();

    float lS, lO, rS, rO;
    if (t > 0) { lS = eRs[pb][t-1]; lO = eRo[pb][t-1]; }
    else       { lS = hLs[i] + hLs[i+1] + hLs[i+2];
                 lO = hLo[i] + hLo[i+1] + hLo[i+2]; }
    if (t < TPB-1) { rS = eLs[pb][t+1]; rO = eLo[pb][t+1]; }
    else           { rS = hRs[i] + hRs[i+1] + hRs[i+2];
                     rO = hRo[i] + hRo[i+1] + hRo[i+2]; }

    #pragma unroll
    for (int k = 0; k < TC; ++k) {
      const float cl  = (k == 0)    ? lS : cs[k-1];
      const float cr  = (k == TC-1) ? rS : cs[k+1];
      const float nsS = cl + cs[k] + cr - sb[k];     // 8-neighbor sum of seg
      const float col = (k == 0)    ? lO : co[k-1];
      const float cor = (k == TC-1) ? rO : co[k+1];
      const float nsO = col + co[k] + cor - ob[k];   // 8-neighbor sum of out
      const float w1 = 9.f - nsS;                    // sig_seg_1
      const float m0 = 1.f + nsO;                    // sig_out_0
      const float s = sb[k], o = ob[k];
      acc += w1 * s * __logf(o + 1e-5f) + m0 * (1.f - s) * __logf(1.f - o + 1e-5f);
    }

    #pragma unroll
    for (int k = 0; k < TC; ++k) {
      sa[k] = sb[k]; sb[k] = sc[k];
      oa[k] = ob[k]; ob[k] = oc[k];
    }
  }

  // wave reduce (64 lanes)
  #pragma unroll
  for (int off = 32; off > 0; off >>= 1) acc += __shfl_down(acc, off, 64);

  __shared__ float wsum[TPB / 64];
  if ((t & 63) == 0) wsum[t >> 6] = acc;
  __syncthreads();
  if (t == 0) {
    const float ssum = wsum[0] + wsum[1] + wsum[2] + wsum[3];
    atomicAdd(dsum, ssum * (-1.0f / ((float)H * (float)W)));  // loss = -mean
  }
}

extern "C" void kernel_launch(void* const* d_in, const int* in_sizes, int n_in,
                              void* d_out, int out_size, void* d_ws, size_t ws_size,
                              hipStream_t stream) {
  const float* outp = (const float*)d_in[0];  // out_image
  const float* segp = (const float*)d_in[1];  // segment_image
  float* o = (float*)d_out;
  hipMemsetAsync(o, 0, sizeof(float), stream);   // graph-capturable; re-zero every call
  dim3 grid(NSTRIP, H / R);
  wbce_kernel<<<grid, TPB, 0, stream>>>(outp, segp, o);
}

// Round 2
// 47.632 us; speedup vs baseline: 1.0958x; 1.0958x over previous
//
#include <hip/hip_runtime.h>

#define H 4096
#define W 4096
#define R 8              // rows per block
#define TC 4             // cols per thread
#define TPB 256
#define STRIP (TPB*TC)   // 1024 cols per block
#define NSTRIP (W/STRIP) // 4

__global__ __launch_bounds__(TPB)
void wbce_kernel(const float* __restrict__ outp, const float* __restrict__ segp,
                 float* __restrict__ dsum) {
  const int t     = threadIdx.x;
  const int strip = blockIdx.x;
  const int r0    = blockIdx.y * R;
  const int c0    = strip * STRIP + t * TC;
  const int cL    = c0 - 1;
  const int cR    = c0 + TC;
  const bool lv   = (cL >= 0);
  const bool rv   = (cR < W);

  // rolling 3-row window: interior TC columns (vector) + 2 halo columns (scalar)
  float sa[TC], sb[TC], sc[TC];
  float oa[TC], ob[TC], oc[TC];
  float sLa, sLb, sLc, sRa, sRb, sRc;
  float oLa, oLb, oLc, oRa, oRb, oRc;

  auto loadrow = [&](int ri, float* sv, float* ov,
                     float& sl, float& sr, float& ol, float& orr) {
    if (ri >= 0 && ri < H) {
      const size_t base = (size_t)ri * W;
      const float4 fs = *reinterpret_cast<const float4*>(segp + base + c0);
      const float4 fo = *reinterpret_cast<const float4*>(outp + base + c0);
      sv[0] = fs.x; sv[1] = fs.y; sv[2] = fs.z; sv[3] = fs.w;
      ov[0] = fo.x; ov[1] = fo.y; ov[2] = fo.z; ov[3] = fo.w;
      sl  = lv ? segp[base + cL] : 0.f;
      ol  = lv ? outp[base + cL] : 0.f;
      sr  = rv ? segp[base + cR] : 0.f;
      orr = rv ? outp[base + cR] : 0.f;
    } else {
      sv[0] = sv[1] = sv[2] = sv[3] = 0.f;
      ov[0] = ov[1] = ov[2] = ov[3] = 0.f;
      sl = sr = ol = orr = 0.f;
    }
  };

  loadrow(r0 - 1, sa, oa, sLa, oLa, sRa, oRa);
  loadrow(r0,     sb, ob, sLb, oLb, sRb, oRb);

  float acc = 0.f;

  #pragma unroll
  for (int i = 0; i < R; ++i) {
    const int r = r0 + i;
    loadrow(r + 1, sc, oc, sLc, oLc, sRc, oRc);

    float cs[TC], co[TC];
    #pragma unroll
    for (int k = 0; k < TC; ++k) {
      cs[k] = sa[k] + sb[k] + sc[k];
      co[k] = oa[k] + ob[k] + oc[k];
    }
    const float csL = sLa + sLb + sLc;
    const float csR = sRa + sRb + sRc;
    const float coL = oLa + oLb + oLc;
    const float coR = oRa + oRb + oRc;

    #pragma unroll
    for (int k = 0; k < TC; ++k) {
      const float cl  = (k == 0)    ? csL : cs[k-1];
      const float cr  = (k == TC-1) ? csR : cs[k+1];
      const float nsS = cl + cs[k] + cr - sb[k];     // 8-neighbor sum of seg
      const float col = (k == 0)    ? coL : co[k-1];
      const float cor = (k == TC-1) ? coR : co[k+1];
      const float nsO = col + co[k] + cor - ob[k];   // 8-neighbor sum of out
      const float w1 = 9.f - nsS;                    // sig_seg_1
      const float m0 = 1.f + nsO;                    // sig_out_0
      const float s = sb[k], o = ob[k];
      acc += w1 * s * __logf(o + 1e-5f) + m0 * (1.f - s) * __logf(1.f - o + 1e-5f);
    }

    #pragma unroll
    for (int k = 0; k < TC; ++k) {
      sa[k] = sb[k]; sb[k] = sc[k];
      oa[k] = ob[k]; ob[k] = oc[k];
    }
    sLa = sLb; sLb = sLc;  sRa = sRb; sRb = sRc;
    oLa = oLb; oLb = oLc;  oRa = oRb; oRb = oRc;
  }

  // wave reduce (64 lanes)
  #pragma unroll
  for (int off = 32; off > 0; off >>= 1) acc += __shfl_down(acc, off, 64);

  __shared__ float wsum[TPB / 64];
  if ((t & 63) == 0) wsum[t >> 6] = acc;
  __syncthreads();
  if (t == 0) {
    const float ssum = wsum[0] + wsum[1] + wsum[2] + wsum[3];
    atomicAdd(dsum, ssum * (-1.0f / ((float)H * (float)W)));  // loss = -mean
  }
}

extern "C" void kernel_launch(void* const* d_in, const int* in_sizes, int n_in,
                              void* d_out, int out_size, void* d_ws, size_t ws_size,
                              hipStream_t stream) {
  const float* outp = (const float*)d_in[0];  // out_image
  const float* segp = (const float*)d_in[1];  // segment_image
  float* o = (float*)d_out;
  hipMemsetAsync(o, 0, sizeof(float), stream);   // graph-capturable; re-zero every call
  dim3 grid(NSTRIP, H / R);
  wbce_kernel<<<grid, TPB, 0, stream>>>(outp, segp, o);
}